// Round 1
// baseline (1683.423 us; speedup 1.0000x reference)
//
#include <hip/hip_runtime.h>

// Jansen-Rit neural mass model, R independent regions, Euler integration.
// One lane per region; 20000-step serial loop is the bottleneck (latency/issue
// bound on ~4 waves). All parameter algebra folded into loop-invariant
// constants so the per-step body is 3 sigmoids + ~10 FMAs + 3 float2 stores.

#define RLOG2E 1.44269504088896340736f

__global__ __launch_bounds__(64)
void jansen_kernel(const float* __restrict__ init_state,
                   const float* __restrict__ p_dt,
                   const int*   __restrict__ p_nsteps,
                   const float* __restrict__ pA,    const float* __restrict__ pa,
                   const float* __restrict__ pB,    const float* __restrict__ pb,
                   const float* __restrict__ pc1,   const float* __restrict__ pc2,
                   const float* __restrict__ pc3,   const float* __restrict__ pc4,
                   const float* __restrict__ pvmax, const float* __restrict__ pv0,
                   const float* __restrict__ pr,    const float* __restrict__ pstd,
                   float* __restrict__ out, int R)
{
    const int reg = blockIdx.x * 64 + threadIdx.x;
    if (reg >= R) return;

    const float dt     = *p_dt;
    const int   nsteps = *p_nsteps;
    const float A = *pA, a = *pa, B = *pB, b = *pb;
    const float c1 = *pc1, c2 = *pc2, c3 = *pc3, c4 = *pc4;
    const float vmax = *pvmax, v0 = *pv0, rsl = *pr, std_in = *pstd;

    // sig(x) = vmax / (1 + exp(r*(v0-x))) = vmax * rcp(1 + exp2(cl2*(v0-x)))
    const float cl2 = rsl * RLOG2E;
    const float cv0 = cl2 * v0;
    const float nE  = -cl2;        // arg = fma(nE,  E-I, cv0)
    const float nM1 = -cl2 * c1;   // arg = fma(nM1, M,   cv0)
    const float nM3 = -cl2 * c3;   // arg = fma(nM3, M,   cv0)

    // Euler update folded: Xv' = kXv*Xv + kSig*rcp + kX*X (+ kIn)
    const float kMv = 1.0f - 2.0f * a * dt;
    const float kIv = 1.0f - 2.0f * b * dt;
    const float kM  = -dt * a * a;
    const float kI  = -dt * b * b;
    const float kSE  = dt * A * a * vmax;
    const float kSM1 = dt * A * a * c2 * vmax;
    const float kSM3 = dt * B * b * c4 * vmax;
    const float kIn  = dt * A * a * std_in;

    float M  = init_state[reg * 6 + 0];
    float E  = init_state[reg * 6 + 1];
    float I  = init_state[reg * 6 + 2];
    float Mv = init_state[reg * 6 + 3];
    float Ev = init_state[reg * 6 + 4];
    float Iv = init_state[reg * 6 + 5];

    const int R6 = R * 6;
    float* hist = out + R6 + (size_t)reg * 6;  // history follows state_vals

    for (int s = 0; s < nsteps; ++s) {
        // sigmoids on the OLD state
        float eE  = __builtin_amdgcn_exp2f(fmaf(nE,  E - I, cv0));
        float eM1 = __builtin_amdgcn_exp2f(fmaf(nM1, M,     cv0));
        float eM3 = __builtin_amdgcn_exp2f(fmaf(nM3, M,     cv0));
        float rE  = __builtin_amdgcn_rcpf(1.0f + eE);
        float rM1 = __builtin_amdgcn_rcpf(1.0f + eM1);
        float rM3 = __builtin_amdgcn_rcpf(1.0f + eM3);

        float nMv = fmaf(kMv, Mv, fmaf(kSE,  rE,  kM * M));
        float nEv = fmaf(kMv, Ev, fmaf(kSM1, rM1, fmaf(kM, E, kIn)));
        float nIv = fmaf(kIv, Iv, fmaf(kSM3, rM3, kI * I));
        float nM  = fmaf(dt, Mv, M);
        float nEx = fmaf(dt, Ev, E);
        float nI  = fmaf(dt, Iv, I);
        M = nM; E = nEx; I = nI; Mv = nMv; Ev = nEv; Iv = nIv;

        float* p = hist + (size_t)s * R6;
        ((float2*)p)[0] = make_float2(M, E);
        ((float2*)p)[1] = make_float2(I, Mv);
        ((float2*)p)[2] = make_float2(Ev, Iv);
    }

    float* fin = out + reg * 6;
    ((float2*)fin)[0] = make_float2(M, E);
    ((float2*)fin)[1] = make_float2(I, Mv);
    ((float2*)fin)[2] = make_float2(Ev, Iv);
}

extern "C" void kernel_launch(void* const* d_in, const int* in_sizes, int n_in,
                              void* d_out, int out_size, void* d_ws, size_t ws_size,
                              hipStream_t stream)
{
    const float* init = (const float*)d_in[0];
    const float* dt   = (const float*)d_in[1];
    const int*   ns   = (const int*)d_in[2];
    const int R = in_sizes[0] / 6;  // 200

    dim3 grid((R + 63) / 64), block(64);
    jansen_kernel<<<grid, block, 0, stream>>>(
        init, dt, ns,
        (const float*)d_in[3],  (const float*)d_in[4],
        (const float*)d_in[5],  (const float*)d_in[6],
        (const float*)d_in[7],  (const float*)d_in[8],
        (const float*)d_in[9],  (const float*)d_in[10],
        (const float*)d_in[11], (const float*)d_in[12],
        (const float*)d_in[13], (const float*)d_in[14],
        (float*)d_out, R);
}

// Round 2
// 1473.608 us; speedup vs baseline: 1.1424x; 1.1424x over previous
//
#include <hip/hip_runtime.h>

// Jansen-Rit neural mass model, R independent regions, Euler integration.
// One lane per region (4 wave64s total). Serial 20000-step loop.
// R2: unroll-by-16 so history stores come from per-step SSA registers --
// breaks the store->next-iteration WAR hazard that serialized R1 at
// ~202 cyc/step on store-completion latency.

#define RLOG2E 1.44269504088896340736f

__global__ __launch_bounds__(64)
void jansen_kernel(const float* __restrict__ init_state,
                   const float* __restrict__ p_dt,
                   const int*   __restrict__ p_nsteps,
                   const float* __restrict__ pA,    const float* __restrict__ pa,
                   const float* __restrict__ pB,    const float* __restrict__ pb,
                   const float* __restrict__ pc1,   const float* __restrict__ pc2,
                   const float* __restrict__ pc3,   const float* __restrict__ pc4,
                   const float* __restrict__ pvmax, const float* __restrict__ pv0,
                   const float* __restrict__ pr,    const float* __restrict__ pstd,
                   float* __restrict__ out, int R)
{
    const int reg = blockIdx.x * 64 + threadIdx.x;
    if (reg >= R) return;

    const float dt     = *p_dt;
    const int   nsteps = *p_nsteps;
    const float A = *pA, a = *pa, B = *pB, b = *pb;
    const float c1 = *pc1, c2 = *pc2, c3 = *pc3, c4 = *pc4;
    const float vmax = *pvmax, v0 = *pv0, rsl = *pr, std_in = *pstd;

    // sig(x) = vmax / (1 + exp(r*(v0-x))) = vmax * rcp(1 + exp2(cl2*(v0-x)))
    const float cl2 = rsl * RLOG2E;
    const float cv0 = cl2 * v0;
    const float nE  = -cl2;        // arg = fma(nE,  E-I, cv0)
    const float nM1 = -cl2 * c1;   // arg = fma(nM1, M,   cv0)
    const float nM3 = -cl2 * c3;   // arg = fma(nM3, M,   cv0)

    // Euler update folded: Xv' = kXv*Xv + kSig*rcp + kX*X (+ kIn)
    const float kMv = 1.0f - 2.0f * a * dt;
    const float kIv = 1.0f - 2.0f * b * dt;
    const float kM  = -dt * a * a;
    const float kI  = -dt * b * b;
    const float kSE  = dt * A * a * vmax;
    const float kSM1 = dt * A * a * c2 * vmax;
    const float kSM3 = dt * B * b * c4 * vmax;
    const float kIn  = dt * A * a * std_in;

    float M  = init_state[reg * 6 + 0];
    float E  = init_state[reg * 6 + 1];
    float I  = init_state[reg * 6 + 2];
    float Mv = init_state[reg * 6 + 3];
    float Ev = init_state[reg * 6 + 4];
    float Iv = init_state[reg * 6 + 5];

    const int R6 = R * 6;
    float* hist = out + R6 + (size_t)reg * 6;  // history follows state_vals

    #define STEP()                                                              \
    do {                                                                        \
        float eE  = __builtin_amdgcn_exp2f(fmaf(nE,  E - I, cv0));              \
        float eM1 = __builtin_amdgcn_exp2f(fmaf(nM1, M,     cv0));              \
        float eM3 = __builtin_amdgcn_exp2f(fmaf(nM3, M,     cv0));              \
        float rE  = __builtin_amdgcn_rcpf(1.0f + eE);                           \
        float rM1 = __builtin_amdgcn_rcpf(1.0f + eM1);                          \
        float rM3 = __builtin_amdgcn_rcpf(1.0f + eM3);                          \
        float nMv_ = fmaf(kMv, Mv, fmaf(kSE,  rE,  kM * M));                    \
        float nEv_ = fmaf(kMv, Ev, fmaf(kSM1, rM1, fmaf(kM, E, kIn)));          \
        float nIv_ = fmaf(kIv, Iv, fmaf(kSM3, rM3, kI * I));                    \
        float nM_  = fmaf(dt, Mv, M);                                           \
        float nE_  = fmaf(dt, Ev, E);                                           \
        float nI_  = fmaf(dt, Iv, I);                                           \
        M = nM_; E = nE_; I = nI_; Mv = nMv_; Ev = nEv_; Iv = nIv_;             \
        ((float2*)hist)[0] = make_float2(M, E);                                 \
        ((float2*)hist)[1] = make_float2(I, Mv);                                \
        ((float2*)hist)[2] = make_float2(Ev, Iv);                               \
        hist += R6;                                                             \
    } while (0)

    const int UN = 16;
    int s = 0;
    for (; s + UN <= nsteps; s += UN) {
        #pragma unroll
        for (int u = 0; u < UN; ++u) {
            STEP();
        }
    }
    for (; s < nsteps; ++s) {
        STEP();
    }
    #undef STEP

    float* fin = out + reg * 6;
    ((float2*)fin)[0] = make_float2(M, E);
    ((float2*)fin)[1] = make_float2(I, Mv);
    ((float2*)fin)[2] = make_float2(Ev, Iv);
}

extern "C" void kernel_launch(void* const* d_in, const int* in_sizes, int n_in,
                              void* d_out, int out_size, void* d_ws, size_t ws_size,
                              hipStream_t stream)
{
    const float* init = (const float*)d_in[0];
    const float* dt   = (const float*)d_in[1];
    const int*   ns   = (const int*)d_in[2];
    const int R = in_sizes[0] / 6;  // 200

    dim3 grid((R + 63) / 64), block(64);
    jansen_kernel<<<grid, block, 0, stream>>>(
        init, dt, ns,
        (const float*)d_in[3],  (const float*)d_in[4],
        (const float*)d_in[5],  (const float*)d_in[6],
        (const float*)d_in[7],  (const float*)d_in[8],
        (const float*)d_in[9],  (const float*)d_in[10],
        (const float*)d_in[11], (const float*)d_in[12],
        (const float*)d_in[13], (const float*)d_in[14],
        (float*)d_out, R);
}